// Round 3
// baseline (302.922 us; speedup 1.0000x reference)
//
#include <hip/hip_runtime.h>
#include <stdint.h>

typedef __attribute__((ext_vector_type(8))) short short8;
typedef __attribute__((ext_vector_type(4))) float f32x4;

#define NEG_FLT_MAX (-3.402823466e38f)

__device__ __forceinline__ unsigned short f2bf(float f) {
  uint32_t u = __float_as_uint(f);
  uint32_t r = (u + 0x7fffu + ((u >> 16) & 1u)) >> 16;
  return (unsigned short)r;
}

__device__ __forceinline__ void gload16(const void* g, void* l) {
  __builtin_amdgcn_global_load_lds(
      (const __attribute__((address_space(1))) uint32_t*)g,
      (__attribute__((address_space(3))) uint32_t*)l, 16, 0, 0);
}

__device__ __forceinline__ short8 ldsf(const unsigned short* p, int boff) {
  return *(const short8*)((const char*)p + boff);
}

// ---------------- weight transpose + fp32->bf16 (+scale fold) ----------------
__global__ void transpose_bf16_kernel(const float* __restrict__ src,
                                      unsigned short* __restrict__ dst,
                                      int R, int C, float scale) {
  __shared__ float tile[32][33];
  const int c0 = blockIdx.x * 32;
  const int r0 = blockIdx.y * 32;
  const int tx = threadIdx.x, ty = threadIdx.y;  // 32 x 8
#pragma unroll
  for (int i = ty; i < 32; i += 8)
    tile[i][tx] = src[(size_t)(r0 + i) * C + (c0 + tx)];
  __syncthreads();
#pragma unroll
  for (int i = ty; i < 32; i += 8)
    dst[(size_t)(c0 + i) * R + (r0 + tx)] = f2bf(tile[tx][i] * scale);
}

// ---------------- block reduction helper ----------------
__device__ __forceinline__ void block_reduce2(float& s, float& ss, float* red) {
#pragma unroll
  for (int off = 32; off > 0; off >>= 1) {
    s += __shfl_xor(s, off);
    ss += __shfl_xor(ss, off);
  }
  const int wave = threadIdx.x >> 6;
  const int lane = threadIdx.x & 63;
  if (lane == 0) { red[wave * 2] = s; red[wave * 2 + 1] = ss; }
  __syncthreads();
  if (threadIdx.x == 0) {
    float a = 0.f, b = 0.f;
    for (int i = 0; i < 4; i++) { a += red[i * 2]; b += red[i * 2 + 1]; }
    red[0] = a; red[1] = b;
  }
  __syncthreads();
  s = red[0]; ss = red[1];
}

// ---------------- LN vit: [18432][1024] f32 -> bf16 ----------------
__global__ __launch_bounds__(256) void ln_vit_kernel(
    const float* __restrict__ x, const float* __restrict__ w,
    const float* __restrict__ b, unsigned short* __restrict__ out) {
  __shared__ float red[8];
  const int row = blockIdx.x;
  const int t = threadIdx.x;
  const float4 v = ((const float4*)(x + (size_t)row * 1024))[t];
  float s = v.x + v.y + v.z + v.w;
  float ss = v.x * v.x + v.y * v.y + v.z * v.z + v.w * v.w;
  block_reduce2(s, ss, red);
  const float m = s * (1.f / 1024.f);
  const float var = ss * (1.f / 1024.f) - m * m;
  const float rstd = rsqrtf(var + 1e-5f);
  const float4 w4 = ((const float4*)w)[t];
  const float4 b4 = ((const float4*)b)[t];
  ushort4 o;
  o.x = f2bf((v.x - m) * rstd * w4.x + b4.x);
  o.y = f2bf((v.y - m) * rstd * w4.y + b4.y);
  o.z = f2bf((v.z - m) * rstd * w4.z + b4.z);
  o.w = f2bf((v.w - m) * rstd * w4.w + b4.w);
  ((ushort4*)(out + (size_t)row * 1024))[t] = o;
}

// ---------------- LN box: [3200][1536] f32 -> two bf16 outputs ----------------
__global__ __launch_bounds__(256) void ln_box_kernel(
    const float* __restrict__ x,
    const float* __restrict__ kw, const float* __restrict__ kb,
    const float* __restrict__ vw, const float* __restrict__ vb,
    unsigned short* __restrict__ kn, unsigned short* __restrict__ vn) {
  __shared__ float red[8];
  const int row = blockIdx.x;
  const int t = threadIdx.x;
  const float4* xr = (const float4*)(x + (size_t)row * 1536);
  const float4 a = xr[t];
  float4 c = make_float4(0.f, 0.f, 0.f, 0.f);
  if (t < 128) c = xr[256 + t];
  float s = a.x + a.y + a.z + a.w + c.x + c.y + c.z + c.w;
  float ss = a.x * a.x + a.y * a.y + a.z * a.z + a.w * a.w +
             c.x * c.x + c.y * c.y + c.z * c.z + c.w * c.w;
  block_reduce2(s, ss, red);
  const float m = s * (1.f / 1536.f);
  const float var = ss * (1.f / 1536.f) - m * m;
  const float rstd = rsqrtf(var + 1e-5f);
  {
    const float4 w4 = ((const float4*)kw)[t];
    const float4 b4 = ((const float4*)kb)[t];
    ushort4 o;
    o.x = f2bf((a.x - m) * rstd * w4.x + b4.x);
    o.y = f2bf((a.y - m) * rstd * w4.y + b4.y);
    o.z = f2bf((a.z - m) * rstd * w4.z + b4.z);
    o.w = f2bf((a.w - m) * rstd * w4.w + b4.w);
    ((ushort4*)(kn + (size_t)row * 1536))[t] = o;
    const float4 w4v = ((const float4*)vw)[t];
    const float4 b4v = ((const float4*)vb)[t];
    o.x = f2bf((a.x - m) * rstd * w4v.x + b4v.x);
    o.y = f2bf((a.y - m) * rstd * w4v.y + b4v.y);
    o.z = f2bf((a.z - m) * rstd * w4v.z + b4v.z);
    o.w = f2bf((a.w - m) * rstd * w4v.w + b4v.w);
    ((ushort4*)(vn + (size_t)row * 1536))[t] = o;
  }
  if (t < 128) {
    const int t2 = 256 + t;
    const float4 w4 = ((const float4*)kw)[t2];
    const float4 b4 = ((const float4*)kb)[t2];
    ushort4 o;
    o.x = f2bf((c.x - m) * rstd * w4.x + b4.x);
    o.y = f2bf((c.y - m) * rstd * w4.y + b4.y);
    o.z = f2bf((c.z - m) * rstd * w4.z + b4.z);
    o.w = f2bf((c.w - m) * rstd * w4.w + b4.w);
    ((ushort4*)(kn + (size_t)row * 1536))[t2] = o;
    const float4 w4v = ((const float4*)vw)[t2];
    const float4 b4v = ((const float4*)vb)[t2];
    o.x = f2bf((c.x - m) * rstd * w4v.x + b4v.x);
    o.y = f2bf((c.y - m) * rstd * w4v.y + b4v.y);
    o.z = f2bf((c.z - m) * rstd * w4v.z + b4v.z);
    o.w = f2bf((c.w - m) * rstd * w4v.w + b4v.w);
    ((ushort4*)(vn + (size_t)row * 1536))[t2] = o;
  }
}

// ================= 3-buffer pipelined GEMM: 256x128 tile, BK=64 =================
// C = A[M,K]*Bt[N,K]^T + bias, bf16 in/out. 512 threads = 8 waves (4M x 2N),
// per-wave 64x64 output (4x4 frags of 16x16x32).
// LDS: 3 rotating buffers x (A 256x64 + B 128x64) bf16 = 144 KiB (dynamic).
// Race-free by construction: block j reads buf[j%3], stages tile j+2 into
// buf[(j+2)%3] which held tile j-1, fully consumed before block j-1's end
// barrier (each wave's MFMAs consumed its ds_reads before reaching it).
// Gate: end-of-block vmcnt(6) confirms tile j+1 (6 loads/tile), leaves this
// block's 6 in flight. Never drains to 0 except the tail block.
// T2 swizzle: LDS row byte r*128 + (cb^(r&7))*16 via pre-permuted global src.

#define STG(mat, ld, rowmax, grow0, k0, ldsoff) do {                       \
    int gr_ = (grow0) + (t >> 3); if (gr_ > (rowmax)) gr_ = (rowmax);      \
    gload16((mat) + (size_t)gr_ * (ld) + (k0) + sc, lds + (ldsoff) + wb);  \
  } while (0)

#define VM6 asm volatile("s_waitcnt vmcnt(6)" ::: "memory")
#define VM0 asm volatile("s_waitcnt vmcnt(0)" ::: "memory")
#define NOOP ((void)0)

#define PH(pA, pB, qm, qn, STAGE, GATE) do {                               \
  const int ab_ = aB + (qm) * 4096;                                        \
  const int bb_ = bB + (qn) * 4096;                                        \
  short8 a00 = ldsf(pA, ab_ + ck0);                                        \
  short8 a01 = ldsf(pA, ab_ + 2048 + ck0);                                 \
  short8 a10 = ldsf(pA, ab_ + ck1);                                        \
  short8 a11 = ldsf(pA, ab_ + 2048 + ck1);                                 \
  short8 b00 = ldsf(pB, bb_ + ck0);                                        \
  short8 b01 = ldsf(pB, bb_ + 2048 + ck0);                                 \
  short8 b10 = ldsf(pB, bb_ + ck1);                                        \
  short8 b11 = ldsf(pB, bb_ + 2048 + ck1);                                 \
  STAGE;                                                                   \
  __builtin_amdgcn_sched_barrier(0);                                       \
  __builtin_amdgcn_s_barrier();                                            \
  __builtin_amdgcn_sched_barrier(0);                                       \
  __builtin_amdgcn_s_setprio(1);                                           \
  acc[(qm)*2+0][(qn)*2+0] = __builtin_amdgcn_mfma_f32_16x16x32_bf16(a00, b00, acc[(qm)*2+0][(qn)*2+0], 0, 0, 0); \
  acc[(qm)*2+0][(qn)*2+1] = __builtin_amdgcn_mfma_f32_16x16x32_bf16(a00, b01, acc[(qm)*2+0][(qn)*2+1], 0, 0, 0); \
  acc[(qm)*2+1][(qn)*2+0] = __builtin_amdgcn_mfma_f32_16x16x32_bf16(a01, b00, acc[(qm)*2+1][(qn)*2+0], 0, 0, 0); \
  acc[(qm)*2+1][(qn)*2+1] = __builtin_amdgcn_mfma_f32_16x16x32_bf16(a01, b01, acc[(qm)*2+1][(qn)*2+1], 0, 0, 0); \
  acc[(qm)*2+0][(qn)*2+0] = __builtin_amdgcn_mfma_f32_16x16x32_bf16(a10, b10, acc[(qm)*2+0][(qn)*2+0], 0, 0, 0); \
  acc[(qm)*2+0][(qn)*2+1] = __builtin_amdgcn_mfma_f32_16x16x32_bf16(a10, b11, acc[(qm)*2+0][(qn)*2+1], 0, 0, 0); \
  acc[(qm)*2+1][(qn)*2+0] = __builtin_amdgcn_mfma_f32_16x16x32_bf16(a11, b10, acc[(qm)*2+1][(qn)*2+0], 0, 0, 0); \
  acc[(qm)*2+1][(qn)*2+1] = __builtin_amdgcn_mfma_f32_16x16x32_bf16(a11, b11, acc[(qm)*2+1][(qn)*2+1], 0, 0, 0); \
  __builtin_amdgcn_s_setprio(0);                                           \
  __builtin_amdgcn_sched_barrier(0);                                       \
  GATE;                                                                    \
  __builtin_amdgcn_s_barrier();                                            \
  asm volatile("" ::: "memory");                                           \
} while (0)

__global__ __launch_bounds__(512, 2) void gemm3p_kernel(
    const unsigned short* __restrict__ A, const unsigned short* __restrict__ Bt,
    const float* __restrict__ bias, unsigned short* __restrict__ C,
    int M, int N, int K) {
  extern __shared__ unsigned short lds[];
  const int t = threadIdx.x;
  const int w = t >> 6, l = t & 63;
  const int wr = w >> 1, wc = w & 1;
  const int lo = l & 15, hi = l >> 4;
  const int tm0 = blockIdx.x * 256, tn0 = blockIdx.y * 128;
  const int Mm1 = M - 1, Nm1 = N - 1;
  const int sc = (((t & 7) ^ ((t >> 3) & 7)) << 3);  // pre-swizzled global col (elems)
  const int wb = w << 9;                              // wave base within issue (elems)
  const int aB = (wr * 64 + lo) * 128;                // A row byte base
  const int bB = (wc * 64 + lo) * 128;                // B row byte base
  const int ck0 = (hi << 4) ^ ((l & 7) << 4);         // swizzled k-bytes, half 0
  const int ck1 = ck0 ^ 64;                           // half 1

  f32x4 acc[4][4];
#pragma unroll
  for (int i = 0; i < 4; i++)
#pragma unroll
    for (int j = 0; j < 4; j++) acc[i][j] = (f32x4)0.0f;

  // prologue: stage tile 0 -> buf0, tile 1 -> buf1 (6 loads each)
  STG(A,  K, Mm1, tm0,        0, 0);
  STG(A,  K, Mm1, tm0 + 64,   0, 4096);
  STG(A,  K, Mm1, tm0 + 128,  0, 8192);
  STG(A,  K, Mm1, tm0 + 192,  0, 12288);
  STG(Bt, K, Nm1, tn0,        0, 16384);
  STG(Bt, K, Nm1, tn0 + 64,   0, 20480);
  STG(A,  K, Mm1, tm0,       64, 24576);
  STG(A,  K, Mm1, tm0 + 64,  64, 28672);
  STG(A,  K, Mm1, tm0 + 128, 64, 32768);
  STG(A,  K, Mm1, tm0 + 192, 64, 36864);
  STG(Bt, K, Nm1, tn0,       64, 40960);
  STG(Bt, K, Nm1, tn0 + 64,  64, 45056);
  VM6;
  __builtin_amdgcn_s_barrier();
  asm volatile("" ::: "memory");

  const int nt = K >> 6;  // requires K % 64 == 0 and nt >= 3
  int cur = 0, nxt2 = 2;
  for (int j = 0; j < nt - 2; ++j) {
    const unsigned short* pA = lds + cur * 24576;
    const unsigned short* pB = pA + 16384;
    const int so = nxt2 * 24576;
    const int ks = (j + 2) << 6;
    PH(pA, pB, 0, 0, { STG(A, K, Mm1, tm0,       ks, so);         STG(A, K, Mm1, tm0 + 64,  ks, so + 4096); }, NOOP);
    PH(pA, pB, 0, 1, { STG(A, K, Mm1, tm0 + 128, ks, so + 8192);  STG(A, K, Mm1, tm0 + 192, ks, so + 12288); }, NOOP);
    PH(pA, pB, 1, 0, { STG(Bt, K, Nm1, tn0,      ks, so + 16384); }, NOOP);
    PH(pA, pB, 1, 1, { STG(Bt, K, Nm1, tn0 + 64, ks, so + 20480); }, VM6);
    cur = (cur == 2) ? 0 : cur + 1;
    nxt2 = (nxt2 == 2) ? 0 : nxt2 + 1;
  }
  {  // block nt-2: no stage; drain remaining tile's loads
    const unsigned short* pA = lds + cur * 24576;
    const unsigned short* pB = pA + 16384;
    PH(pA, pB, 0, 0, NOOP, NOOP);
    PH(pA, pB, 0, 1, NOOP, NOOP);
    PH(pA, pB, 1, 0, NOOP, NOOP);
    PH(pA, pB, 1, 1, NOOP, VM0);
    cur = (cur == 2) ? 0 : cur + 1;
  }
  {  // block nt-1: last tile
    const unsigned short* pA = lds + cur * 24576;
    const unsigned short* pB = pA + 16384;
    PH(pA, pB, 0, 0, NOOP, NOOP);
    PH(pA, pB, 0, 1, NOOP, NOOP);
    PH(pA, pB, 1, 0, NOOP, NOOP);
    PH(pA, pB, 1, 1, NOOP, NOOP);
  }

  // epilogue: C write + bias
#pragma unroll
  for (int fi = 0; fi < 4; fi++) {
    const int row0 = tm0 + wr * 64 + fi * 16 + hi * 4;
#pragma unroll
    for (int fj = 0; fj < 4; fj++) {
      const int col = tn0 + wc * 64 + fj * 16 + lo;
      const float bv = bias[col];
#pragma unroll
      for (int r = 0; r < 4; r++) {
        const int row = row0 + r;
        if (row < M) C[(size_t)row * N + col] = f2bf(acc[fi][fj][r] + bv);
      }
    }
  }
}

// ---------------- GEMM core (128x128, m97-style) — used by K/V/att kernels ----------
__device__ __forceinline__ void gemm_core(
    const unsigned short* __restrict__ A, int lda, int rowmaxA, int tm0,
    const unsigned short* __restrict__ Bt, int ldb, int rowmaxB, int tn0,
    int K, unsigned short* As, unsigned short* Bs, f32x4 acc[4][4]) {
  const int tid = threadIdx.x;
  const int w = tid >> 6, l = tid & 63;
  const int wr = w >> 1, wc = w & 1;
  const int srow = (w << 4) + (l >> 2);
  const int scol = (l & 3) << 3;
  int ra0 = tm0 + srow;      if (ra0 > rowmaxA) ra0 = rowmaxA;
  int ra1 = tm0 + srow + 64; if (ra1 > rowmaxA) ra1 = rowmaxA;
  int rb0 = tn0 + srow;      if (rb0 > rowmaxB) rb0 = rowmaxB;
  int rb1 = tn0 + srow + 64; if (rb1 > rowmaxB) rb1 = rowmaxB;
  const unsigned short* pa0 = A + (size_t)ra0 * lda + scol;
  const unsigned short* pa1 = A + (size_t)ra1 * lda + scol;
  const unsigned short* pb0 = Bt + (size_t)rb0 * ldb + scol;
  const unsigned short* pb1 = Bt + (size_t)rb1 * ldb + scol;
  unsigned short* la0 = As + (w << 4) * 32;
  unsigned short* la1 = As + ((w << 4) + 64) * 32;
  unsigned short* lb0 = Bs + (w << 4) * 32;
  unsigned short* lb1 = Bs + ((w << 4) + 64) * 32;
  const int foff = ((l & 15) << 5) + ((l >> 4) << 3);
  const unsigned short* fa = As + (wr << 6) * 32 + foff;
  const unsigned short* fb = Bs + (wc << 6) * 32 + foff;
#pragma unroll
  for (int i = 0; i < 4; i++)
#pragma unroll
    for (int j = 0; j < 4; j++) acc[i][j] = (f32x4)0.0f;
  for (int k0 = 0; k0 < K; k0 += 32) {
    gload16(pa0 + k0, la0);
    gload16(pa1 + k0, la1);
    gload16(pb0 + k0, lb0);
    gload16(pb1 + k0, lb1);
    __syncthreads();
    short8 a[4], b[4];
#pragma unroll
    for (int i = 0; i < 4; i++) a[i] = *(const short8*)(fa + i * 16 * 32);
#pragma unroll
    for (int j = 0; j < 4; j++) b[j] = *(const short8*)(fb + j * 16 * 32);
#pragma unroll
    for (int i = 0; i < 4; i++)
#pragma unroll
      for (int j = 0; j < 4; j++)
        acc[i][j] = __builtin_amdgcn_mfma_f32_16x16x32_bf16(a[i], b[j], acc[i][j], 0, 0, 0);
    __syncthreads();
  }
}

// ---------------- QKV projection GEMM (K/V): bf16 out (+bias), opt transposed write ---
__global__ __launch_bounds__(256) void gemm_qkv_kernel(
    const unsigned short* __restrict__ A, const unsigned short* __restrict__ Bt,
    const float* __restrict__ bias, float bscale,
    unsigned short* __restrict__ C, int M, int N, int K,
    int trans, int rpb, int tld) {
  __shared__ unsigned short As[128 * 32];
  __shared__ unsigned short Bs[128 * 32];
  const int tm0 = blockIdx.x * 128, tn0 = blockIdx.y * 128;
  f32x4 acc[4][4];
  gemm_core(A, K, M - 1, tm0, Bt, K, N - 1, tn0, K, As, Bs, acc);
  const int tid = threadIdx.x;
  const int w = tid >> 6, l = tid & 63;
  const int wr = w >> 1, wc = w & 1;
#pragma unroll
  for (int i = 0; i < 4; i++) {
    const int row0 = tm0 + wr * 64 + i * 16 + (l >> 4) * 4;
#pragma unroll
    for (int j = 0; j < 4; j++) {
      const int col = tn0 + wc * 64 + j * 16 + (l & 15);
      const float bv = bias[col] * bscale;
#pragma unroll
      for (int r = 0; r < 4; r++) {
        const int row = row0 + r;
        const float val = acc[i][j][r] + bv;
        if (!trans) {
          if (row < M) C[(size_t)row * N + col] = f2bf(val);
        } else {
          if (row < M) {
            const int bb = row / rpb;
            const int ll = row - bb * rpb;
            C[((size_t)bb * N + col) * tld + ll] = f2bf(val);
          }
        }
      }
    }
  }
}

// ---------------- ATT1: logits = q.k^T (scale prefolded), mask, softmax -> bf16 att ----
__global__ __launch_bounds__(256) void att1_kernel(
    const unsigned short* __restrict__ q, const unsigned short* __restrict__ k,
    const int* __restrict__ lengths, unsigned short* __restrict__ att) {
  __shared__ __align__(16) char smem[104 * 132 * 4];
  unsigned short* As = (unsigned short*)smem;
  unsigned short* Bs = As + 128 * 32;
  float* Smat = (float*)smem;  // [104][132]: Smat[c*132 + row]
  const int b = blockIdx.y;
  const int tm0 = blockIdx.x * 128;
  f32x4 acc[4][4];
  gemm_core(q + (size_t)b * 576 * 1024, 1024, 575, tm0,
            k + (size_t)b * 100 * 1024, 1024, 99, 0, 1024, As, Bs, acc);
  __syncthreads();
  const int tid = threadIdx.x;
  const int w = tid >> 6, l = tid & 63;
  const int wr = w >> 1, wc = w & 1;
#pragma unroll
  for (int i = 0; i < 4; i++) {
#pragma unroll
    for (int j = 0; j < 4; j++) {
      const int c = wc * 64 + j * 16 + (l & 15);
      if (c < 104) {
        const int lr0 = wr * 64 + i * 16 + (l >> 4) * 4;
#pragma unroll
        for (int r = 0; r < 4; r++) Smat[(size_t)c * 132 + lr0 + r] = acc[i][j][r];
      }
    }
  }
  __syncthreads();
  const int t = tid;
  if (t < 128) {
    const int row = tm0 + t;
    if (row < 576) {
      const int len = lengths[b];
      float mx = NEG_FLT_MAX;
      for (int ll = 0; ll < 100; ll++) {
        const float v = (ll < len) ? Smat[ll * 132 + t] : NEG_FLT_MAX;
        mx = fmaxf(mx, v);
      }
      float sum = 0.f;
      for (int ll = 0; ll < 100; ll++) {
        const float v = (ll < len) ? Smat[ll * 132 + t] : NEG_FLT_MAX;
        const float e = __expf(v - mx);
        Smat[ll * 132 + t] = e;
        sum += e;
      }
      const float inv = 1.f / sum;
      unsigned short* arow = att + ((size_t)b * 576 + row) * 128;
      for (int ll = 0; ll < 100; ll++) arow[ll] = f2bf(Smat[ll * 132 + t] * inv);
      for (int ll = 100; ll < 128; ll++) arow[ll] = 0;
    }
  }
}

// ---------------- ATT2: out = att @ v + vit (fp32 out) ----------------
__global__ __launch_bounds__(256) void att2_kernel(
    const unsigned short* __restrict__ att, const unsigned short* __restrict__ vT,
    const float* __restrict__ vit, float* __restrict__ out) {
  __shared__ unsigned short As[128 * 32];
  __shared__ unsigned short Bs[128 * 32];
  const int b = blockIdx.z;
  const int tm0 = blockIdx.x * 128, tn0 = blockIdx.y * 128;
  f32x4 acc[4][4];
  gemm_core(att + (size_t)b * 576 * 128, 128, 575, tm0,
            vT + (size_t)b * 1024 * 128, 128, 1023, tn0, 128, As, Bs, acc);
  const int tid = threadIdx.x;
  const int w = tid >> 6, l = tid & 63;
  const int wr = w >> 1, wc = w & 1;
#pragma unroll
  for (int i = 0; i < 4; i++) {
    const int row0 = tm0 + wr * 64 + i * 16 + (l >> 4) * 4;
#pragma unroll
    for (int j = 0; j < 4; j++) {
      const int col = tn0 + wc * 64 + j * 16 + (l & 15);
#pragma unroll
      for (int r = 0; r < 4; r++) {
        const int row = row0 + r;
        if (row < 576) {
          const size_t idx = ((size_t)b * 576 + row) * 1024 + col;
          out[idx] = acc[i][j][r] + vit[idx];
        }
      }
    }
  }
}

extern "C" void kernel_launch(void* const* d_in, const int* in_sizes, int n_in,
                              void* d_out, int out_size, void* d_ws, size_t ws_size,
                              hipStream_t stream) {
  const float* vit = (const float*)d_in[0];
  const float* box = (const float*)d_in[1];
  const int* lengths = (const int*)d_in[2];
  const float* q_ln_w = (const float*)d_in[3];
  const float* q_ln_b = (const float*)d_in[4];
  const float* q_w = (const float*)d_in[5];
  const float* q_b = (const float*)d_in[6];
  const float* k_ln_w = (const float*)d_in[7];
  const float* k_ln_b = (const float*)d_in[8];
  const float* k_w = (const float*)d_in[9];
  const float* k_b = (const float*)d_in[10];
  const float* v_ln_w = (const float*)d_in[11];
  const float* v_ln_b = (const float*)d_in[12];
  const float* v_w = (const float*)d_in[13];
  const float* v_b = (const float*)d_in[14];
  float* out = (float*)d_out;
  char* ws = (char*)d_ws;

  unsigned short* q    = (unsigned short*)(ws + 0);          // [18432][1024] bf16
  unsigned short* kn   = (unsigned short*)(ws + 0);          // [3200][1536]
  unsigned short* vn   = (unsigned short*)(ws + 9830400);    // [3200][1536]
  unsigned short* k_wt = (unsigned short*)(ws + 37748736);   // [1024][1536]
  unsigned short* v_wt = (unsigned short*)(ws + 40894464);   // [1024][1536]
  unsigned short* q_wt = (unsigned short*)(ws + 44040192);   // [1024][1024]
  unsigned short* kk   = (unsigned short*)(ws + 46137344);   // [3200][1024]
  unsigned short* vT   = (unsigned short*)(ws + 52690944);   // [32][1024][128]
  unsigned short* att  = (unsigned short*)(ws + 61079552);   // [32][576][128]
  unsigned short* qn   = (unsigned short*)d_out;             // bf16 scratch in output buf

  const float scale = 0.03125f;  // 1/sqrt(1024)
  dim3 tb(32, 8);

  // allow 144 KiB dynamic LDS for the pipelined GEMM
  (void)hipFuncSetAttribute((const void*)gemm3p_kernel,
                            hipFuncAttributeMaxDynamicSharedMemorySize, 147456);

  // 1. weights: transpose + convert (+fold scale into k)
  transpose_bf16_kernel<<<dim3(32, 32), tb, 0, stream>>>(q_w, q_wt, 1024, 1024, 1.0f);
  transpose_bf16_kernel<<<dim3(32, 48), tb, 0, stream>>>(k_w, k_wt, 1536, 1024, scale);
  transpose_bf16_kernel<<<dim3(32, 48), tb, 0, stream>>>(v_w, v_wt, 1536, 1024, 1.0f);

  // 2. LN box (shared stats, two outputs)
  ln_box_kernel<<<3200, 256, 0, stream>>>(box, k_ln_w, k_ln_b, v_ln_w, v_ln_b, kn, vn);

  // 3. K and V projections (V written transposed into [B][1024][128], l-padded)
  gemm_qkv_kernel<<<dim3(25, 8), 256, 0, stream>>>(kn, k_wt, k_b, scale, kk, 3200, 1024, 1536, 0, 0, 0);
  gemm_qkv_kernel<<<dim3(25, 8), 256, 0, stream>>>(vn, v_wt, v_b, 1.0f, vT, 3200, 1024, 1536, 1, 100, 128);

  // 4. LN vit -> qn (scratch in d_out)
  ln_vit_kernel<<<18432, 256, 0, stream>>>(vit, q_ln_w, q_ln_b, qn);

  // 5. Q projection: 3-buffer pipelined 256x128 GEMM
  gemm3p_kernel<<<dim3(72, 8), 512, 147456, stream>>>(qn, q_wt, q_b, q, 18432, 1024, 1024);

  // 6. attention scores + masked softmax -> bf16 att [B][576][128]
  att1_kernel<<<dim3(5, 32), 256, 0, stream>>>(q, kk, lengths, att);

  // 7. out = att @ v + vit
  att2_kernel<<<dim3(5, 8, 32), 256, 0, stream>>>(att, vT, vit, out);

  (void)in_sizes; (void)n_in; (void)out_size; (void)ws_size;
}

// Round 4
// 231.977 us; speedup vs baseline: 1.3058x; 1.3058x over previous
//
#include <hip/hip_runtime.h>
#include <stdint.h>

typedef __attribute__((ext_vector_type(8))) short short8;
typedef __attribute__((ext_vector_type(4))) float f32x4;

#define NEG_FLT_MAX (-3.402823466e38f)

__device__ __forceinline__ unsigned short f2bf(float f) {
  uint32_t u = __float_as_uint(f);
  uint32_t r = (u + 0x7fffu + ((u >> 16) & 1u)) >> 16;
  return (unsigned short)r;
}

__device__ __forceinline__ void gload16(const void* g, void* l) {
  __builtin_amdgcn_global_load_lds(
      (const __attribute__((address_space(1))) uint32_t*)g,
      (__attribute__((address_space(3))) uint32_t*)l, 16, 0, 0);
}

// ---------------- merged weight transposes: fp32->bf16, [R][C] -> [C][R] ----------------
__global__ void tp3_kernel(const float* __restrict__ qw, const float* __restrict__ kw,
                           const float* __restrict__ vw,
                           unsigned short* __restrict__ qwt, unsigned short* __restrict__ kwt,
                           unsigned short* __restrict__ vwt, float kscale) {
  __shared__ float tile[32][33];
  const int z = blockIdx.z;
  const float* src = (z == 0) ? qw : (z == 1) ? kw : vw;
  unsigned short* dst = (z == 0) ? qwt : (z == 1) ? kwt : vwt;
  const int R = (z == 0) ? 1024 : 1536;
  const float scale = (z == 1) ? kscale : 1.0f;
  const int C = 1024;
  const int c0 = blockIdx.x * 32;
  const int r0 = blockIdx.y * 32;
  if (r0 >= R) return;
  const int tx = threadIdx.x, ty = threadIdx.y;  // 32 x 8
#pragma unroll
  for (int i = ty; i < 32; i += 8)
    tile[i][tx] = src[(size_t)(r0 + i) * C + (c0 + tx)];
  __syncthreads();
#pragma unroll
  for (int i = ty; i < 32; i += 8)
    dst[(size_t)(c0 + i) * R + (r0 + tx)] = f2bf(tile[tx][i] * scale);
}

// ---------------- block reduction helper ----------------
__device__ __forceinline__ void block_reduce2(float& s, float& ss, float* red) {
#pragma unroll
  for (int off = 32; off > 0; off >>= 1) {
    s += __shfl_xor(s, off);
    ss += __shfl_xor(ss, off);
  }
  const int wave = threadIdx.x >> 6;
  const int lane = threadIdx.x & 63;
  if (lane == 0) { red[wave * 2] = s; red[wave * 2 + 1] = ss; }
  __syncthreads();
  if (threadIdx.x == 0) {
    float a = 0.f, b = 0.f;
    for (int i = 0; i < 4; i++) { a += red[i * 2]; b += red[i * 2 + 1]; }
    red[0] = a; red[1] = b;
  }
  __syncthreads();
  s = red[0]; ss = red[1];
}

// ---------------- LN vit: [18432][1024] f32 -> bf16 ----------------
__global__ __launch_bounds__(256) void ln_vit_kernel(
    const float* __restrict__ x, const float* __restrict__ w,
    const float* __restrict__ b, unsigned short* __restrict__ out) {
  __shared__ float red[8];
  const int row = blockIdx.x;
  const int t = threadIdx.x;
  const float4 v = ((const float4*)(x + (size_t)row * 1024))[t];
  float s = v.x + v.y + v.z + v.w;
  float ss = v.x * v.x + v.y * v.y + v.z * v.z + v.w * v.w;
  block_reduce2(s, ss, red);
  const float m = s * (1.f / 1024.f);
  const float var = ss * (1.f / 1024.f) - m * m;
  const float rstd = rsqrtf(var + 1e-5f);
  const float4 w4 = ((const float4*)w)[t];
  const float4 b4 = ((const float4*)b)[t];
  ushort4 o;
  o.x = f2bf((v.x - m) * rstd * w4.x + b4.x);
  o.y = f2bf((v.y - m) * rstd * w4.y + b4.y);
  o.z = f2bf((v.z - m) * rstd * w4.z + b4.z);
  o.w = f2bf((v.w - m) * rstd * w4.w + b4.w);
  ((ushort4*)(out + (size_t)row * 1024))[t] = o;
}

// ---------------- LN box: [3200][1536] f32 -> two bf16 outputs ----------------
__global__ __launch_bounds__(256) void ln_box_kernel(
    const float* __restrict__ x,
    const float* __restrict__ kw, const float* __restrict__ kb,
    const float* __restrict__ vw, const float* __restrict__ vb,
    unsigned short* __restrict__ kn, unsigned short* __restrict__ vn) {
  __shared__ float red[8];
  const int row = blockIdx.x;
  const int t = threadIdx.x;
  const float4* xr = (const float4*)(x + (size_t)row * 1536);
  const float4 a = xr[t];
  float4 c = make_float4(0.f, 0.f, 0.f, 0.f);
  if (t < 128) c = xr[256 + t];
  float s = a.x + a.y + a.z + a.w + c.x + c.y + c.z + c.w;
  float ss = a.x * a.x + a.y * a.y + a.z * a.z + a.w * a.w +
             c.x * c.x + c.y * c.y + c.z * c.z + c.w * c.w;
  block_reduce2(s, ss, red);
  const float m = s * (1.f / 1536.f);
  const float var = ss * (1.f / 1536.f) - m * m;
  const float rstd = rsqrtf(var + 1e-5f);
  {
    const float4 w4 = ((const float4*)kw)[t];
    const float4 b4 = ((const float4*)kb)[t];
    ushort4 o;
    o.x = f2bf((a.x - m) * rstd * w4.x + b4.x);
    o.y = f2bf((a.y - m) * rstd * w4.y + b4.y);
    o.z = f2bf((a.z - m) * rstd * w4.z + b4.z);
    o.w = f2bf((a.w - m) * rstd * w4.w + b4.w);
    ((ushort4*)(kn + (size_t)row * 1536))[t] = o;
    const float4 w4v = ((const float4*)vw)[t];
    const float4 b4v = ((const float4*)vb)[t];
    o.x = f2bf((a.x - m) * rstd * w4v.x + b4v.x);
    o.y = f2bf((a.y - m) * rstd * w4v.y + b4v.y);
    o.z = f2bf((a.z - m) * rstd * w4v.z + b4v.z);
    o.w = f2bf((a.w - m) * rstd * w4v.w + b4v.w);
    ((ushort4*)(vn + (size_t)row * 1536))[t] = o;
  }
  if (t < 128) {
    const int t2 = 256 + t;
    const float4 w4 = ((const float4*)kw)[t2];
    const float4 b4 = ((const float4*)kb)[t2];
    ushort4 o;
    o.x = f2bf((c.x - m) * rstd * w4.x + b4.x);
    o.y = f2bf((c.y - m) * rstd * w4.y + b4.y);
    o.z = f2bf((c.z - m) * rstd * w4.z + b4.z);
    o.w = f2bf((c.w - m) * rstd * w4.w + b4.w);
    ((ushort4*)(kn + (size_t)row * 1536))[t2] = o;
    const float4 w4v = ((const float4*)vw)[t2];
    const float4 b4v = ((const float4*)vb)[t2];
    o.x = f2bf((c.x - m) * rstd * w4v.x + b4v.x);
    o.y = f2bf((c.y - m) * rstd * w4v.y + b4v.y);
    o.z = f2bf((c.z - m) * rstd * w4v.z + b4v.z);
    o.w = f2bf((c.w - m) * rstd * w4v.w + b4v.w);
    ((ushort4*)(vn + (size_t)row * 1536))[t2] = o;
  }
}

// ---------------- GEMM core (128x128, m97-style) ----------
__device__ __forceinline__ void gemm_core(
    const unsigned short* __restrict__ A, int lda, int rowmaxA, int tm0,
    const unsigned short* __restrict__ Bt, int ldb, int rowmaxB, int tn0,
    int K, unsigned short* As, unsigned short* Bs, f32x4 acc[4][4]) {
  const int tid = threadIdx.x;
  const int w = tid >> 6, l = tid & 63;
  const int wr = w >> 1, wc = w & 1;
  const int srow = (w << 4) + (l >> 2);
  const int scol = (l & 3) << 3;
  int ra0 = tm0 + srow;      if (ra0 > rowmaxA) ra0 = rowmaxA;
  int ra1 = tm0 + srow + 64; if (ra1 > rowmaxA) ra1 = rowmaxA;
  int rb0 = tn0 + srow;      if (rb0 > rowmaxB) rb0 = rowmaxB;
  int rb1 = tn0 + srow + 64; if (rb1 > rowmaxB) rb1 = rowmaxB;
  const unsigned short* pa0 = A + (size_t)ra0 * lda + scol;
  const unsigned short* pa1 = A + (size_t)ra1 * lda + scol;
  const unsigned short* pb0 = Bt + (size_t)rb0 * ldb + scol;
  const unsigned short* pb1 = Bt + (size_t)rb1 * ldb + scol;
  unsigned short* la0 = As + (w << 4) * 32;
  unsigned short* la1 = As + ((w << 4) + 64) * 32;
  unsigned short* lb0 = Bs + (w << 4) * 32;
  unsigned short* lb1 = Bs + ((w << 4) + 64) * 32;
  const int foff = ((l & 15) << 5) + ((l >> 4) << 3);
  const unsigned short* fa = As + (wr << 6) * 32 + foff;
  const unsigned short* fb = Bs + (wc << 6) * 32 + foff;
#pragma unroll
  for (int i = 0; i < 4; i++)
#pragma unroll
    for (int j = 0; j < 4; j++) acc[i][j] = (f32x4)0.0f;
  for (int k0 = 0; k0 < K; k0 += 32) {
    gload16(pa0 + k0, la0);
    gload16(pa1 + k0, la1);
    gload16(pb0 + k0, lb0);
    gload16(pb1 + k0, lb1);
    __syncthreads();
    short8 a[4], b[4];
#pragma unroll
    for (int i = 0; i < 4; i++) a[i] = *(const short8*)(fa + i * 16 * 32);
#pragma unroll
    for (int j = 0; j < 4; j++) b[j] = *(const short8*)(fb + j * 16 * 32);
#pragma unroll
    for (int i = 0; i < 4; i++)
#pragma unroll
      for (int j = 0; j < 4; j++)
        acc[i][j] = __builtin_amdgcn_mfma_f32_16x16x32_bf16(a[i], b[j], acc[i][j], 0, 0, 0);
    __syncthreads();
  }
}

// ---------------- Q projection GEMM: bf16 out (+bias) ----------------
__global__ __launch_bounds__(256) void gemm_qkv_kernel(
    const unsigned short* __restrict__ A, const unsigned short* __restrict__ Bt,
    const float* __restrict__ bias, unsigned short* __restrict__ C,
    int M, int N, int K) {
  __shared__ unsigned short As[128 * 32];
  __shared__ unsigned short Bs[128 * 32];
  const int tm0 = blockIdx.x * 128, tn0 = blockIdx.y * 128;
  f32x4 acc[4][4];
  gemm_core(A, K, M - 1, tm0, Bt, K, N - 1, tn0, K, As, Bs, acc);
  const int tid = threadIdx.x;
  const int w = tid >> 6, l = tid & 63;
  const int wr = w >> 1, wc = w & 1;
#pragma unroll
  for (int i = 0; i < 4; i++) {
    const int row0 = tm0 + wr * 64 + i * 16 + (l >> 4) * 4;
#pragma unroll
    for (int j = 0; j < 4; j++) {
      const int col = tn0 + wc * 64 + j * 16 + (l & 15);
      const float bv = bias[col];
#pragma unroll
      for (int r = 0; r < 4; r++) {
        const int row = row0 + r;
        if (row < M) C[(size_t)row * N + col] = f2bf(acc[i][j][r] + bv);
      }
    }
  }
}

// ---------------- K+V projections in one grid (z selects) ----------------
__global__ __launch_bounds__(256) void gemm_kv_kernel(
    const unsigned short* __restrict__ kn, const unsigned short* __restrict__ vn,
    const unsigned short* __restrict__ kwt, const unsigned short* __restrict__ vwt,
    const float* __restrict__ kb, const float* __restrict__ vb, float kscale,
    unsigned short* __restrict__ kk, unsigned short* __restrict__ vT) {
  __shared__ unsigned short As[128 * 32];
  __shared__ unsigned short Bs[128 * 32];
  const int z = blockIdx.z;
  const unsigned short* A = z ? vn : kn;
  const unsigned short* Bt = z ? vwt : kwt;
  const float* bias = z ? vb : kb;
  const float bscale = z ? 1.0f : kscale;
  const int M = 3200, N = 1024, K = 1536;
  const int tm0 = blockIdx.x * 128, tn0 = blockIdx.y * 128;
  f32x4 acc[4][4];
  gemm_core(A, K, M - 1, tm0, Bt, K, N - 1, tn0, K, As, Bs, acc);
  const int tid = threadIdx.x;
  const int w = tid >> 6, l = tid & 63;
  const int wr = w >> 1, wc = w & 1;
#pragma unroll
  for (int i = 0; i < 4; i++) {
    const int row0 = tm0 + wr * 64 + i * 16 + (l >> 4) * 4;
#pragma unroll
    for (int j = 0; j < 4; j++) {
      const int col = tn0 + wc * 64 + j * 16 + (l & 15);
      const float bv = bias[col] * bscale;
#pragma unroll
      for (int r = 0; r < 4; r++) {
        const int row = row0 + r;
        const float val = acc[i][j][r] + bv;
        if (!z) {
          kk[(size_t)row * N + col] = f2bf(val);
        } else {
          const int bb = row / 100;
          const int ll = row - bb * 100;
          vT[((size_t)bb * N + col) * 128 + ll] = f2bf(val);
        }
      }
    }
  }
}

// ---------------- ATT1: 64-row q-tiles, 288 blocks; QK^T + masked softmax -> bf16 ----
// 256 threads = 4 waves; wave w computes S[64 x 32] slice (cols w*32..w*32+31).
// Softmax: 4 lanes per row (t = r*4+g), shfl_xor combine.
__global__ __launch_bounds__(256) void att1_kernel(
    const unsigned short* __restrict__ q, const unsigned short* __restrict__ kk,
    const int* __restrict__ lengths, unsigned short* __restrict__ att) {
  __shared__ __align__(16) char smem[128 * 68 * 4 + 256];
  unsigned short* As = (unsigned short*)smem;            // [64][32] bf16 (4 KB)
  unsigned short* Bs = (unsigned short*)(smem + 4096);   // [128][32] bf16 (8 KB)
  float* Smat = (float*)smem;                            // [128 cols][68] f32 (aliases)
  float* invr = (float*)(smem + 128 * 68 * 4);           // [64]
  const int b = blockIdx.y;
  const int tm0 = blockIdx.x * 64;
  const int t = threadIdx.x;
  const int w = t >> 6, l = t & 63;
  const unsigned short* A = q + (size_t)b * 576 * 1024;
  const unsigned short* B = kk + (size_t)b * 100 * 1024;
  // staging: thread t -> row t>>2, col8 (t&3)*8 ; LDS dst = base + w*512 (+ lane*8 by HW)
  const int sr = t >> 2;
  const int sc8 = (t & 3) << 3;
  const unsigned short* pa = A + (size_t)(tm0 + sr) * 1024 + sc8;
  const unsigned short* pb0 = B + (size_t)sr * 1024 + sc8;
  int rb1 = 64 + sr; if (rb1 > 99) rb1 = 99;
  const unsigned short* pb1 = B + (size_t)rb1 * 1024 + sc8;
  unsigned short* la = As + (w << 9);
  unsigned short* lb0 = Bs + (w << 9);
  unsigned short* lb1 = Bs + 2048 + (w << 9);
  const int foff = ((l & 15) << 5) + ((l >> 4) << 3);
  const unsigned short* fa = As + foff;
  const unsigned short* fb = Bs + (w << 5) * 32 + foff;

  f32x4 acc[4][2];
#pragma unroll
  for (int i = 0; i < 4; i++) { acc[i][0] = (f32x4)0.0f; acc[i][1] = (f32x4)0.0f; }

  for (int k0 = 0; k0 < 1024; k0 += 32) {
    gload16(pa + k0, la);
    gload16(pb0 + k0, lb0);
    gload16(pb1 + k0, lb1);
    __syncthreads();
    short8 a[4], bf[2];
#pragma unroll
    for (int i = 0; i < 4; i++) a[i] = *(const short8*)(fa + i * 512);
#pragma unroll
    for (int j = 0; j < 2; j++) bf[j] = *(const short8*)(fb + j * 512);
#pragma unroll
    for (int i = 0; i < 4; i++)
#pragma unroll
      for (int j = 0; j < 2; j++)
        acc[i][j] = __builtin_amdgcn_mfma_f32_16x16x32_bf16(a[i], bf[j], acc[i][j], 0, 0, 0);
    __syncthreads();
  }

  // store S col-major: Smat[c][r], stride 68
#pragma unroll
  for (int i = 0; i < 4; i++) {
    const int r0 = i * 16 + (l >> 4) * 4;
#pragma unroll
    for (int j = 0; j < 2; j++) {
      const int c = (w << 5) + j * 16 + (l & 15);
#pragma unroll
      for (int rr = 0; rr < 4; rr++) Smat[c * 68 + r0 + rr] = acc[i][j][rr];
    }
  }
  __syncthreads();

  // softmax: 4 lanes per row; lane g handles cols g*25..g*25+24
  const int r = t >> 2, g = t & 3;
  const int len = lengths[b];
  float mx = NEG_FLT_MAX;
#pragma unroll
  for (int i = 0; i < 25; i++) {
    const int ll = g * 25 + i;
    const float v = (ll < len) ? Smat[ll * 68 + r] : NEG_FLT_MAX;
    mx = fmaxf(mx, v);
  }
  mx = fmaxf(mx, __shfl_xor(mx, 1));
  mx = fmaxf(mx, __shfl_xor(mx, 2));
  float sum = 0.f;
#pragma unroll
  for (int i = 0; i < 25; i++) {
    const int ll = g * 25 + i;
    const float v = (ll < len) ? Smat[ll * 68 + r] : NEG_FLT_MAX;
    const float e = __expf(v - mx);
    Smat[ll * 68 + r] = e;
    sum += e;
  }
  sum += __shfl_xor(sum, 1);
  sum += __shfl_xor(sum, 2);
  if (g == 0) invr[r] = 1.f / sum;
  __syncthreads();

  // write att row r, cols g*32..g*32+31 as 8x ushort4
  const float inv = invr[r];
  unsigned short* arow = att + ((size_t)b * 576 + tm0 + r) * 128;
#pragma unroll
  for (int j = 0; j < 8; j++) {
    const int c0 = g * 32 + j * 4;
    ushort4 o;
    o.x = (c0 + 0 < 100) ? f2bf(Smat[(c0 + 0) * 68 + r] * inv) : (unsigned short)0;
    o.y = (c0 + 1 < 100) ? f2bf(Smat[(c0 + 1) * 68 + r] * inv) : (unsigned short)0;
    o.z = (c0 + 2 < 100) ? f2bf(Smat[(c0 + 2) * 68 + r] * inv) : (unsigned short)0;
    o.w = (c0 + 3 < 100) ? f2bf(Smat[(c0 + 3) * 68 + r] * inv) : (unsigned short)0;
    ((ushort4*)arow)[g * 8 + j] = o;
  }
}

// ---------------- ATT2: out = att @ v + vit (fp32 out) ----------------
__global__ __launch_bounds__(256) void att2_kernel(
    const unsigned short* __restrict__ att, const unsigned short* __restrict__ vT,
    const float* __restrict__ vit, float* __restrict__ out) {
  __shared__ unsigned short As[128 * 32];
  __shared__ unsigned short Bs[128 * 32];
  const int b = blockIdx.z;
  const int tm0 = blockIdx.x * 128, tn0 = blockIdx.y * 128;
  f32x4 acc[4][4];
  gemm_core(att + (size_t)b * 576 * 128, 128, 575, tm0,
            vT + (size_t)b * 1024 * 128, 128, 1023, tn0, 128, As, Bs, acc);
  const int tid = threadIdx.x;
  const int w = tid >> 6, l = tid & 63;
  const int wr = w >> 1, wc = w & 1;
#pragma unroll
  for (int i = 0; i < 4; i++) {
    const int row0 = tm0 + wr * 64 + i * 16 + (l >> 4) * 4;
#pragma unroll
    for (int j = 0; j < 4; j++) {
      const int col = tn0 + wc * 64 + j * 16 + (l & 15);
#pragma unroll
      for (int r = 0; r < 4; r++) {
        const int row = row0 + r;
        if (row < 576) {
          const size_t idx = ((size_t)b * 576 + row) * 1024 + col;
          out[idx] = acc[i][j][r] + vit[idx];
        }
      }
    }
  }
}

extern "C" void kernel_launch(void* const* d_in, const int* in_sizes, int n_in,
                              void* d_out, int out_size, void* d_ws, size_t ws_size,
                              hipStream_t stream) {
  const float* vit = (const float*)d_in[0];
  const float* box = (const float*)d_in[1];
  const int* lengths = (const int*)d_in[2];
  const float* q_ln_w = (const float*)d_in[3];
  const float* q_ln_b = (const float*)d_in[4];
  const float* q_w = (const float*)d_in[5];
  const float* q_b = (const float*)d_in[6];
  const float* k_ln_w = (const float*)d_in[7];
  const float* k_ln_b = (const float*)d_in[8];
  const float* k_w = (const float*)d_in[9];
  const float* k_b = (const float*)d_in[10];
  const float* v_ln_w = (const float*)d_in[11];
  const float* v_ln_b = (const float*)d_in[12];
  const float* v_w = (const float*)d_in[13];
  const float* v_b = (const float*)d_in[14];
  float* out = (float*)d_out;
  char* ws = (char*)d_ws;

  unsigned short* q    = (unsigned short*)(ws + 0);          // [18432][1024] bf16
  unsigned short* kn   = (unsigned short*)(ws + 0);          // [3200][1536]
  unsigned short* vn   = (unsigned short*)(ws + 9830400);    // [3200][1536]
  unsigned short* k_wt = (unsigned short*)(ws + 37748736);   // [1024][1536]
  unsigned short* v_wt = (unsigned short*)(ws + 40894464);   // [1024][1536]
  unsigned short* q_wt = (unsigned short*)(ws + 44040192);   // [1024][1024]
  unsigned short* kk   = (unsigned short*)(ws + 46137344);   // [3200][1024]
  unsigned short* vT   = (unsigned short*)(ws + 52690944);   // [32][1024][128]
  unsigned short* att  = (unsigned short*)(ws + 61079552);   // [32][576][128]
  unsigned short* qn   = (unsigned short*)d_out;             // bf16 scratch in output buf

  const float scale = 0.03125f;  // 1/sqrt(1024)

  // 1. merged weight transposes (+fold scale into k)
  tp3_kernel<<<dim3(32, 48, 3), dim3(32, 8), 0, stream>>>(
      q_w, k_w, v_w, q_wt, k_wt, v_wt, scale);

  // 2. LN box (shared stats, two outputs)
  ln_box_kernel<<<3200, 256, 0, stream>>>(box, k_ln_w, k_ln_b, v_ln_w, v_ln_b, kn, vn);

  // 3. K and V projections, one grid (V written transposed to [B][1024][128])
  gemm_kv_kernel<<<dim3(25, 8, 2), 256, 0, stream>>>(
      kn, vn, k_wt, v_wt, k_b, v_b, scale, kk, vT);

  // 4. LN vit -> qn (scratch in d_out)
  ln_vit_kernel<<<18432, 256, 0, stream>>>(vit, q_ln_w, q_ln_b, qn);

  // 5. Q projection (proven 128x128 m97 structure)
  gemm_qkv_kernel<<<dim3(144, 8), 256, 0, stream>>>(qn, q_wt, q_b, q, 18432, 1024, 1024);

  // 6. attention scores + masked softmax -> bf16 att [B][576][128]
  att1_kernel<<<dim3(9, 32), 256, 0, stream>>>(q, kk, lengths, att);

  // 7. out = att @ v + vit
  att2_kernel<<<dim3(5, 8, 32), 256, 0, stream>>>(att, vT, vit, out);

  (void)in_sizes; (void)n_in; (void)out_size; (void)ws_size;
}

// Round 5
// 217.947 us; speedup vs baseline: 1.3899x; 1.0644x over previous
//
#include <hip/hip_runtime.h>
#include <stdint.h>

typedef __attribute__((ext_vector_type(8))) short short8;
typedef __attribute__((ext_vector_type(4))) float f32x4;

#define NEG_FLT_MAX (-3.402823466e38f)

__device__ __forceinline__ unsigned short f2bf(float f) {
  uint32_t u = __float_as_uint(f);
  uint32_t r = (u + 0x7fffu + ((u >> 16) & 1u)) >> 16;
  return (unsigned short)r;
}

__device__ __forceinline__ void gload16(const void* g, void* l) {
  __builtin_amdgcn_global_load_lds(
      (const __attribute__((address_space(1))) uint32_t*)g,
      (__attribute__((address_space(3))) uint32_t*)l, 16, 0, 0);
}

// ---------------- merged weight transposes: fp32->bf16, [R][C] -> [C][R] ----------------
__global__ void tp3_kernel(const float* __restrict__ qw, const float* __restrict__ kw,
                           const float* __restrict__ vw,
                           unsigned short* __restrict__ qwt, unsigned short* __restrict__ kwt,
                           unsigned short* __restrict__ vwt, float kscale) {
  __shared__ float tile[32][33];
  const int z = blockIdx.z;
  const float* src = (z == 0) ? qw : (z == 1) ? kw : vw;
  unsigned short* dst = (z == 0) ? qwt : (z == 1) ? kwt : vwt;
  const int R = (z == 0) ? 1024 : 1536;
  const float scale = (z == 1) ? kscale : 1.0f;
  const int C = 1024;
  const int c0 = blockIdx.x * 32;
  const int r0 = blockIdx.y * 32;
  if (r0 >= R) return;
  const int tx = threadIdx.x, ty = threadIdx.y;  // 32 x 8
#pragma unroll
  for (int i = ty; i < 32; i += 8)
    tile[i][tx] = src[(size_t)(r0 + i) * C + (c0 + tx)];
  __syncthreads();
#pragma unroll
  for (int i = ty; i < 32; i += 8)
    dst[(size_t)(c0 + i) * R + (r0 + tx)] = f2bf(tile[tx][i] * scale);
}

// ---------------- block reduction helper ----------------
__device__ __forceinline__ void block_reduce2(float& s, float& ss, float* red) {
#pragma unroll
  for (int off = 32; off > 0; off >>= 1) {
    s += __shfl_xor(s, off);
    ss += __shfl_xor(ss, off);
  }
  const int wave = threadIdx.x >> 6;
  const int lane = threadIdx.x & 63;
  if (lane == 0) { red[wave * 2] = s; red[wave * 2 + 1] = ss; }
  __syncthreads();
  if (threadIdx.x == 0) {
    float a = 0.f, b = 0.f;
    for (int i = 0; i < 4; i++) { a += red[i * 2]; b += red[i * 2 + 1]; }
    red[0] = a; red[1] = b;
  }
  __syncthreads();
  s = red[0]; ss = red[1];
}

// ---------------- LN vit: [18432][1024] f32 -> bf16 ----------------
__global__ __launch_bounds__(256) void ln_vit_kernel(
    const float* __restrict__ x, const float* __restrict__ w,
    const float* __restrict__ b, unsigned short* __restrict__ out) {
  __shared__ float red[8];
  const int row = blockIdx.x;
  const int t = threadIdx.x;
  const float4 v = ((const float4*)(x + (size_t)row * 1024))[t];
  float s = v.x + v.y + v.z + v.w;
  float ss = v.x * v.x + v.y * v.y + v.z * v.z + v.w * v.w;
  block_reduce2(s, ss, red);
  const float m = s * (1.f / 1024.f);
  const float var = ss * (1.f / 1024.f) - m * m;
  const float rstd = rsqrtf(var + 1e-5f);
  const float4 w4 = ((const float4*)w)[t];
  const float4 b4 = ((const float4*)b)[t];
  ushort4 o;
  o.x = f2bf((v.x - m) * rstd * w4.x + b4.x);
  o.y = f2bf((v.y - m) * rstd * w4.y + b4.y);
  o.z = f2bf((v.z - m) * rstd * w4.z + b4.z);
  o.w = f2bf((v.w - m) * rstd * w4.w + b4.w);
  ((ushort4*)(out + (size_t)row * 1024))[t] = o;
}

// ---------------- LN box: [3200][1536] f32 -> two bf16 outputs ----------------
__global__ __launch_bounds__(256) void ln_box_kernel(
    const float* __restrict__ x,
    const float* __restrict__ kw, const float* __restrict__ kb,
    const float* __restrict__ vw, const float* __restrict__ vb,
    unsigned short* __restrict__ kn, unsigned short* __restrict__ vn) {
  __shared__ float red[8];
  const int row = blockIdx.x;
  const int t = threadIdx.x;
  const float4* xr = (const float4*)(x + (size_t)row * 1536);
  const float4 a = xr[t];
  float4 c = make_float4(0.f, 0.f, 0.f, 0.f);
  if (t < 128) c = xr[256 + t];
  float s = a.x + a.y + a.z + a.w + c.x + c.y + c.z + c.w;
  float ss = a.x * a.x + a.y * a.y + a.z * a.z + a.w * a.w +
             c.x * c.x + c.y * c.y + c.z * c.z + c.w * c.w;
  block_reduce2(s, ss, red);
  const float m = s * (1.f / 1536.f);
  const float var = ss * (1.f / 1536.f) - m * m;
  const float rstd = rsqrtf(var + 1e-5f);
  {
    const float4 w4 = ((const float4*)kw)[t];
    const float4 b4 = ((const float4*)kb)[t];
    ushort4 o;
    o.x = f2bf((a.x - m) * rstd * w4.x + b4.x);
    o.y = f2bf((a.y - m) * rstd * w4.y + b4.y);
    o.z = f2bf((a.z - m) * rstd * w4.z + b4.z);
    o.w = f2bf((a.w - m) * rstd * w4.w + b4.w);
    ((ushort4*)(kn + (size_t)row * 1536))[t] = o;
    const float4 w4v = ((const float4*)vw)[t];
    const float4 b4v = ((const float4*)vb)[t];
    o.x = f2bf((a.x - m) * rstd * w4v.x + b4v.x);
    o.y = f2bf((a.y - m) * rstd * w4v.y + b4v.y);
    o.z = f2bf((a.z - m) * rstd * w4v.z + b4v.z);
    o.w = f2bf((a.w - m) * rstd * w4v.w + b4v.w);
    ((ushort4*)(vn + (size_t)row * 1536))[t] = o;
  }
  if (t < 128) {
    const int t2 = 256 + t;
    const float4 w4 = ((const float4*)kw)[t2];
    const float4 b4 = ((const float4*)kb)[t2];
    ushort4 o;
    o.x = f2bf((c.x - m) * rstd * w4.x + b4.x);
    o.y = f2bf((c.y - m) * rstd * w4.y + b4.y);
    o.z = f2bf((c.z - m) * rstd * w4.z + b4.z);
    o.w = f2bf((c.w - m) * rstd * w4.w + b4.w);
    ((ushort4*)(kn + (size_t)row * 1536))[t2] = o;
    const float4 w4v = ((const float4*)vw)[t2];
    const float4 b4v = ((const float4*)vb)[t2];
    o.x = f2bf((c.x - m) * rstd * w4v.x + b4v.x);
    o.y = f2bf((c.y - m) * rstd * w4v.y + b4v.y);
    o.z = f2bf((c.z - m) * rstd * w4v.z + b4v.z);
    o.w = f2bf((c.w - m) * rstd * w4v.w + b4v.w);
    ((ushort4*)(vn + (size_t)row * 1536))[t2] = o;
  }
}

// ---------------- GEMM core, BK=64: two 32-col halves per barrier pair ----------
// LDS: As/Bs each [2][128][32] bf16 (16 KB each). One vmcnt drain per 64-K.
__device__ __forceinline__ void gemm_core64(
    const unsigned short* __restrict__ A, int lda, int rowmaxA, int tm0,
    const unsigned short* __restrict__ Bt, int ldb, int rowmaxB, int tn0,
    int K, unsigned short* As, unsigned short* Bs, f32x4 acc[4][4]) {
  const int tid = threadIdx.x;
  const int w = tid >> 6, l = tid & 63;
  const int wr = w >> 1, wc = w & 1;
  const int srow = (w << 4) + (l >> 2);
  const int scol = (l & 3) << 3;
  int ra0 = tm0 + srow;      if (ra0 > rowmaxA) ra0 = rowmaxA;
  int ra1 = tm0 + srow + 64; if (ra1 > rowmaxA) ra1 = rowmaxA;
  int rb0 = tn0 + srow;      if (rb0 > rowmaxB) rb0 = rowmaxB;
  int rb1 = tn0 + srow + 64; if (rb1 > rowmaxB) rb1 = rowmaxB;
  const unsigned short* pa0 = A + (size_t)ra0 * lda + scol;
  const unsigned short* pa1 = A + (size_t)ra1 * lda + scol;
  const unsigned short* pb0 = Bt + (size_t)rb0 * ldb + scol;
  const unsigned short* pb1 = Bt + (size_t)rb1 * ldb + scol;
  unsigned short* la0 = As + (w << 4) * 32;
  unsigned short* la1 = As + ((w << 4) + 64) * 32;
  unsigned short* lb0 = Bs + (w << 4) * 32;
  unsigned short* lb1 = Bs + ((w << 4) + 64) * 32;
  const int foff = ((l & 15) << 5) + ((l >> 4) << 3);
  const unsigned short* fa = As + (wr << 6) * 32 + foff;
  const unsigned short* fb = Bs + (wc << 6) * 32 + foff;
#pragma unroll
  for (int i = 0; i < 4; i++)
#pragma unroll
    for (int j = 0; j < 4; j++) acc[i][j] = (f32x4)0.0f;
  for (int k0 = 0; k0 < K; k0 += 64) {
    gload16(pa0 + k0, la0);
    gload16(pa1 + k0, la1);
    gload16(pb0 + k0, lb0);
    gload16(pb1 + k0, lb1);
    gload16(pa0 + k0 + 32, la0 + 4096);
    gload16(pa1 + k0 + 32, la1 + 4096);
    gload16(pb0 + k0 + 32, lb0 + 4096);
    gload16(pb1 + k0 + 32, lb1 + 4096);
    __syncthreads();
    {
      short8 a[4], b[4];
#pragma unroll
      for (int i = 0; i < 4; i++) a[i] = *(const short8*)(fa + i * 512);
#pragma unroll
      for (int j = 0; j < 4; j++) b[j] = *(const short8*)(fb + j * 512);
#pragma unroll
      for (int i = 0; i < 4; i++)
#pragma unroll
        for (int j = 0; j < 4; j++)
          acc[i][j] = __builtin_amdgcn_mfma_f32_16x16x32_bf16(a[i], b[j], acc[i][j], 0, 0, 0);
    }
    {
      short8 a[4], b[4];
#pragma unroll
      for (int i = 0; i < 4; i++) a[i] = *(const short8*)(fa + 4096 + i * 512);
#pragma unroll
      for (int j = 0; j < 4; j++) b[j] = *(const short8*)(fb + 4096 + j * 512);
#pragma unroll
      for (int i = 0; i < 4; i++)
#pragma unroll
        for (int j = 0; j < 4; j++)
          acc[i][j] = __builtin_amdgcn_mfma_f32_16x16x32_bf16(a[i], b[j], acc[i][j], 0, 0, 0);
    }
    __syncthreads();
  }
}

// ---------------- Q projection GEMM: bf16 out (+bias), 4 waves/SIMD target ----------
__global__ __launch_bounds__(256, 4) void gemm_qkv_kernel(
    const unsigned short* __restrict__ A, const unsigned short* __restrict__ Bt,
    const float* __restrict__ bias, unsigned short* __restrict__ C,
    int M, int N, int K) {
  __shared__ unsigned short As[128 * 64];
  __shared__ unsigned short Bs[128 * 64];
  const int tm0 = blockIdx.x * 128, tn0 = blockIdx.y * 128;
  f32x4 acc[4][4];
  gemm_core64(A, K, M - 1, tm0, Bt, K, N - 1, tn0, K, As, Bs, acc);
  const int tid = threadIdx.x;
  const int w = tid >> 6, l = tid & 63;
  const int wr = w >> 1, wc = w & 1;
#pragma unroll
  for (int i = 0; i < 4; i++) {
    const int row0 = tm0 + wr * 64 + i * 16 + (l >> 4) * 4;
#pragma unroll
    for (int j = 0; j < 4; j++) {
      const int col = tn0 + wc * 64 + j * 16 + (l & 15);
      const float bv = bias[col];
#pragma unroll
      for (int r = 0; r < 4; r++) {
        const int row = row0 + r;
        if (row < M) C[(size_t)row * N + col] = f2bf(acc[i][j][r] + bv);
      }
    }
  }
}

// ---------------- K+V projections in one grid (z selects) ----------------
__global__ __launch_bounds__(256) void gemm_kv_kernel(
    const unsigned short* __restrict__ kn, const unsigned short* __restrict__ vn,
    const unsigned short* __restrict__ kwt, const unsigned short* __restrict__ vwt,
    const float* __restrict__ kb, const float* __restrict__ vb, float kscale,
    unsigned short* __restrict__ kk, unsigned short* __restrict__ vT) {
  __shared__ unsigned short As[128 * 64];
  __shared__ unsigned short Bs[128 * 64];
  const int z = blockIdx.z;
  const unsigned short* A = z ? vn : kn;
  const unsigned short* Bt = z ? vwt : kwt;
  const float* bias = z ? vb : kb;
  const float bscale = z ? 1.0f : kscale;
  const int M = 3200, N = 1024, K = 1536;
  const int tm0 = blockIdx.x * 128, tn0 = blockIdx.y * 128;
  f32x4 acc[4][4];
  gemm_core64(A, K, M - 1, tm0, Bt, K, N - 1, tn0, K, As, Bs, acc);
  const int tid = threadIdx.x;
  const int w = tid >> 6, l = tid & 63;
  const int wr = w >> 1, wc = w & 1;
#pragma unroll
  for (int i = 0; i < 4; i++) {
    const int row0 = tm0 + wr * 64 + i * 16 + (l >> 4) * 4;
#pragma unroll
    for (int j = 0; j < 4; j++) {
      const int col = tn0 + wc * 64 + j * 16 + (l & 15);
      const float bv = bias[col] * bscale;
#pragma unroll
      for (int r = 0; r < 4; r++) {
        const int row = row0 + r;
        const float val = acc[i][j][r] + bv;
        if (!z) {
          kk[(size_t)row * N + col] = f2bf(val);
        } else {
          const int bb = row / 100;
          const int ll = row - bb * 100;
          vT[((size_t)bb * N + col) * 128 + ll] = f2bf(val);
        }
      }
    }
  }
}

// ---------------- ATT1: 64-row q-tiles; BK=64 QK^T + masked softmax -> bf16 ----
__global__ __launch_bounds__(256) void att1_kernel(
    const unsigned short* __restrict__ q, const unsigned short* __restrict__ kk,
    const int* __restrict__ lengths, unsigned short* __restrict__ att) {
  __shared__ __align__(16) char smem[128 * 68 * 4 + 256];
  unsigned short* As = (unsigned short*)smem;            // [2][64][32] bf16 (8 KB)
  unsigned short* Bs = (unsigned short*)(smem + 8192);   // [2][128][32] bf16 (16 KB)
  float* Smat = (float*)smem;                            // [128 cols][68] f32 (aliases)
  float* invr = (float*)(smem + 128 * 68 * 4);           // [64]
  const int b = blockIdx.y;
  const int tm0 = blockIdx.x * 64;
  const int t = threadIdx.x;
  const int w = t >> 6, l = t & 63;
  const unsigned short* A = q + (size_t)b * 576 * 1024;
  const unsigned short* B = kk + (size_t)b * 100 * 1024;
  const int sr = t >> 2;
  const int sc8 = (t & 3) << 3;
  const unsigned short* pa = A + (size_t)(tm0 + sr) * 1024 + sc8;
  const unsigned short* pb0 = B + (size_t)sr * 1024 + sc8;
  int rb1 = 64 + sr; if (rb1 > 99) rb1 = 99;
  const unsigned short* pb1 = B + (size_t)rb1 * 1024 + sc8;
  unsigned short* la = As + (w << 9);
  unsigned short* lb0 = Bs + (w << 9);
  unsigned short* lb1 = Bs + 2048 + (w << 9);
  const int foff = ((l & 15) << 5) + ((l >> 4) << 3);
  const unsigned short* fa = As + foff;
  const unsigned short* fb = Bs + (w << 5) * 32 + foff;

  f32x4 acc[4][2];
#pragma unroll
  for (int i = 0; i < 4; i++) { acc[i][0] = (f32x4)0.0f; acc[i][1] = (f32x4)0.0f; }

  for (int k0 = 0; k0 < 1024; k0 += 64) {
    gload16(pa + k0, la);
    gload16(pb0 + k0, lb0);
    gload16(pb1 + k0, lb1);
    gload16(pa + k0 + 32, la + 2048);
    gload16(pb0 + k0 + 32, lb0 + 4096);
    gload16(pb1 + k0 + 32, lb1 + 4096);
    __syncthreads();
    {
      short8 a[4], bf[2];
#pragma unroll
      for (int i = 0; i < 4; i++) a[i] = *(const short8*)(fa + i * 512);
#pragma unroll
      for (int j = 0; j < 2; j++) bf[j] = *(const short8*)(fb + j * 512);
#pragma unroll
      for (int i = 0; i < 4; i++)
#pragma unroll
        for (int j = 0; j < 2; j++)
          acc[i][j] = __builtin_amdgcn_mfma_f32_16x16x32_bf16(a[i], bf[j], acc[i][j], 0, 0, 0);
    }
    {
      short8 a[4], bf[2];
#pragma unroll
      for (int i = 0; i < 4; i++) a[i] = *(const short8*)(fa + 2048 + i * 512);
#pragma unroll
      for (int j = 0; j < 2; j++) bf[j] = *(const short8*)(fb + 4096 + j * 512);
#pragma unroll
      for (int i = 0; i < 4; i++)
#pragma unroll
        for (int j = 0; j < 2; j++)
          acc[i][j] = __builtin_amdgcn_mfma_f32_16x16x32_bf16(a[i], bf[j], acc[i][j], 0, 0, 0);
    }
    __syncthreads();
  }

  // store S col-major: Smat[c][r], stride 68
#pragma unroll
  for (int i = 0; i < 4; i++) {
    const int r0 = i * 16 + (l >> 4) * 4;
#pragma unroll
    for (int j = 0; j < 2; j++) {
      const int c = (w << 5) + j * 16 + (l & 15);
#pragma unroll
      for (int rr = 0; rr < 4; rr++) Smat[c * 68 + r0 + rr] = acc[i][j][rr];
    }
  }
  __syncthreads();

  // softmax: 4 lanes per row; lane g handles cols g*25..g*25+24
  const int r = t >> 2, g = t & 3;
  const int len = lengths[b];
  float mx = NEG_FLT_MAX;
#pragma unroll
  for (int i = 0; i < 25; i++) {
    const int ll = g * 25 + i;
    const float v = (ll < len) ? Smat[ll * 68 + r] : NEG_FLT_MAX;
    mx = fmaxf(mx, v);
  }
  mx = fmaxf(mx, __shfl_xor(mx, 1));
  mx = fmaxf(mx, __shfl_xor(mx, 2));
  float sum = 0.f;
#pragma unroll
  for (int i = 0; i < 25; i++) {
    const int ll = g * 25 + i;
    const float v = (ll < len) ? Smat[ll * 68 + r] : NEG_FLT_MAX;
    const float e = __expf(v - mx);
    Smat[ll * 68 + r] = e;
    sum += e;
  }
  sum += __shfl_xor(sum, 1);
  sum += __shfl_xor(sum, 2);
  if (g == 0) invr[r] = 1.f / sum;
  __syncthreads();

  const float inv = invr[r];
  unsigned short* arow = att + ((size_t)b * 576 + tm0 + r) * 128;
#pragma unroll
  for (int j = 0; j < 8; j++) {
    const int c0 = g * 32 + j * 4;
    ushort4 o;
    o.x = (c0 + 0 < 100) ? f2bf(Smat[(c0 + 0) * 68 + r] * inv) : (unsigned short)0;
    o.y = (c0 + 1 < 100) ? f2bf(Smat[(c0 + 1) * 68 + r] * inv) : (unsigned short)0;
    o.z = (c0 + 2 < 100) ? f2bf(Smat[(c0 + 2) * 68 + r] * inv) : (unsigned short)0;
    o.w = (c0 + 3 < 100) ? f2bf(Smat[(c0 + 3) * 68 + r] * inv) : (unsigned short)0;
    ((ushort4*)arow)[g * 8 + j] = o;
  }
}

// ---------------- ATT2: out = att @ v + vit (fp32 out) ----------------
__global__ __launch_bounds__(256) void att2_kernel(
    const unsigned short* __restrict__ att, const unsigned short* __restrict__ vT,
    const float* __restrict__ vit, float* __restrict__ out) {
  __shared__ unsigned short As[128 * 64];
  __shared__ unsigned short Bs[128 * 64];
  const int b = blockIdx.z;
  const int tm0 = blockIdx.x * 128, tn0 = blockIdx.y * 128;
  f32x4 acc[4][4];
  gemm_core64(att + (size_t)b * 576 * 128, 128, 575, tm0,
              vT + (size_t)b * 1024 * 128, 128, 1023, tn0, 128, As, Bs, acc);
  const int tid = threadIdx.x;
  const int w = tid >> 6, l = tid & 63;
  const int wr = w >> 1, wc = w & 1;
#pragma unroll
  for (int i = 0; i < 4; i++) {
    const int row0 = tm0 + wr * 64 + i * 16 + (l >> 4) * 4;
#pragma unroll
    for (int j = 0; j < 4; j++) {
      const int col = tn0 + wc * 64 + j * 16 + (l & 15);
#pragma unroll
      for (int r = 0; r < 4; r++) {
        const int row = row0 + r;
        if (row < 576) {
          const size_t idx = ((size_t)b * 576 + row) * 1024 + col;
          out[idx] = acc[i][j][r] + vit[idx];
        }
      }
    }
  }
}

extern "C" void kernel_launch(void* const* d_in, const int* in_sizes, int n_in,
                              void* d_out, int out_size, void* d_ws, size_t ws_size,
                              hipStream_t stream) {
  const float* vit = (const float*)d_in[0];
  const float* box = (const float*)d_in[1];
  const int* lengths = (const int*)d_in[2];
  const float* q_ln_w = (const float*)d_in[3];
  const float* q_ln_b = (const float*)d_in[4];
  const float* q_w = (const float*)d_in[5];
  const float* q_b = (const float*)d_in[6];
  const float* k_ln_w = (const float*)d_in[7];
  const float* k_ln_b = (const float*)d_in[8];
  const float* k_w = (const float*)d_in[9];
  const float* k_b = (const float*)d_in[10];
  const float* v_ln_w = (const float*)d_in[11];
  const float* v_ln_b = (const float*)d_in[12];
  const float* v_w = (const float*)d_in[13];
  const float* v_b = (const float*)d_in[14];
  float* out = (float*)d_out;
  char* ws = (char*)d_ws;

  unsigned short* q    = (unsigned short*)(ws + 0);          // [18432][1024] bf16
  unsigned short* kn   = (unsigned short*)(ws + 0);          // [3200][1536]
  unsigned short* vn   = (unsigned short*)(ws + 9830400);    // [3200][1536]
  unsigned short* k_wt = (unsigned short*)(ws + 37748736);   // [1024][1536]
  unsigned short* v_wt = (unsigned short*)(ws + 40894464);   // [1024][1536]
  unsigned short* q_wt = (unsigned short*)(ws + 44040192);   // [1024][1024]
  unsigned short* kk   = (unsigned short*)(ws + 46137344);   // [3200][1024]
  unsigned short* vT   = (unsigned short*)(ws + 52690944);   // [32][1024][128]
  unsigned short* att  = (unsigned short*)(ws + 61079552);   // [32][576][128]
  unsigned short* qn   = (unsigned short*)d_out;             // bf16 scratch in output buf

  const float scale = 0.03125f;  // 1/sqrt(1024)

  // 1. merged weight transposes (+fold scale into k)
  tp3_kernel<<<dim3(32, 48, 3), dim3(32, 8), 0, stream>>>(
      q_w, k_w, v_w, q_wt, k_wt, v_wt, scale);

  // 2. LN box (shared stats, two outputs)
  ln_box_kernel<<<3200, 256, 0, stream>>>(box, k_ln_w, k_ln_b, v_ln_w, v_ln_b, kn, vn);

  // 3. K and V projections, one grid (V written transposed to [B][1024][128])
  gemm_kv_kernel<<<dim3(25, 8, 2), 256, 0, stream>>>(
      kn, vn, k_wt, v_wt, k_b, v_b, scale, kk, vT);

  // 4. LN vit -> qn (scratch in d_out)
  ln_vit_kernel<<<18432, 256, 0, stream>>>(vit, q_ln_w, q_ln_b, qn);

  // 5. Q projection (BK=64, 4 waves/SIMD)
  gemm_qkv_kernel<<<dim3(144, 8), 256, 0, stream>>>(qn, q_wt, q_b, q, 18432, 1024, 1024);

  // 6. attention scores + masked softmax -> bf16 att [B][576][128]
  att1_kernel<<<dim3(9, 32), 256, 0, stream>>>(q, kk, lengths, att);

  // 7. out = att @ v + vit
  att2_kernel<<<dim3(5, 8, 32), 256, 0, stream>>>(att, vT, vit, out);

  (void)in_sizes; (void)n_in; (void)out_size; (void)ws_size;
}